// Round 3
// baseline (375.285 us; speedup 1.0000x reference)
//
#include <hip/hip_runtime.h>
#include <hip/hip_bf16.h>

#define B_   4
#define C_   256
#define N_   4096   // H*W
#define NH_  4
#define HD_  64
#define G_   32
#define CPG_ 8      // C_/G_
#define EPS_ 1e-5f

typedef __bf16 bf16x8 __attribute__((ext_vector_type(8)));
typedef __bf16 bf16x4 __attribute__((ext_vector_type(4)));
typedef float  f32x4  __attribute__((ext_vector_type(4)));
typedef unsigned int u32x4 __attribute__((ext_vector_type(4)));
typedef unsigned int u32x2 __attribute__((ext_vector_type(2)));

#define EXP2F(x) __builtin_amdgcn_exp2f(x)   // v_exp_f32: D = 2^S0

static __device__ __forceinline__ unsigned int packbf(float a, float b) {
    __bf16 x = (__bf16)a, y = (__bf16)b;
    unsigned short ux = __builtin_bit_cast(unsigned short, x);
    unsigned short uy = __builtin_bit_cast(unsigned short, y);
    return (unsigned int)ux | ((unsigned int)uy << 16);
}

// ---------------- GroupNorm: fp32 [b][c][n] -> normalized bf16 X^T [b][n][c] -----
// Transposed output makes GEMM A-fragments direct 16B loads (no LDS staging).
__global__ __launch_bounds__(256) void gn_kernel(const float* __restrict__ in,
                                                 const float* __restrict__ gw,
                                                 const float* __restrict__ gb,
                                                 __bf16* __restrict__ out) {
    const int b = blockIdx.x / G_;
    const int g = blockIdx.x % G_;
    const int tid = threadIdx.x;
    const size_t base = ((size_t)b * C_ + g * CPG_) * N_;
    const float4* pv = (const float4*)(in + base);
    const int NC = (CPG_ * N_) / 4;

    float s = 0.f, ss = 0.f;
    for (int i = tid; i < NC; i += 256) {
        float4 v = pv[i];
        s  += v.x + v.y + v.z + v.w;
        ss += v.x * v.x + v.y * v.y + v.z * v.z + v.w * v.w;
    }
    #pragma unroll
    for (int m = 32; m >= 1; m >>= 1) { s += __shfl_xor(s, m); ss += __shfl_xor(ss, m); }
    __shared__ float red[8];
    const int w = tid >> 6;
    if ((tid & 63) == 0) { red[w] = s; red[4 + w] = ss; }
    __syncthreads();
    s  = red[0] + red[1] + red[2] + red[3];
    ss = red[4] + red[5] + red[6] + red[7];
    const float mean = s * (1.f / 32768.f);
    const float var  = ss * (1.f / 32768.f) - mean * mean;
    const float rinv = rsqrtf(var + EPS_);

    // fold per-channel scale/shift: o = v*sc[j] + sh[j]
    float sc[CPG_], sh[CPG_];
    #pragma unroll
    for (int j = 0; j < CPG_; j++) {
        const float gm = gw[g * CPG_ + j], bt = gb[g * CPG_ + j];
        sc[j] = rinv * gm;
        sh[j] = bt - mean * rinv * gm;
    }
    __bf16* ob = out + (size_t)b * N_ * C_ + g * CPG_;
    for (int n = tid; n < N_; n += 256) {        // 16 iters; per-instr loads coalesce over n
        bf16x8 o;
        #pragma unroll
        for (int j = 0; j < CPG_; j++) {
            const float v = in[base + (size_t)j * N_ + n];
            o[j] = (__bf16)(v * sc[j] + sh[j]);
        }
        *(bf16x8*)(ob + (size_t)n * C_) = o;     // 16B per lane, L2 merges rows
    }
}

// ---------------- conv1x1 GEMM: LDS-free main loop -------------------------------
// X^T [b][n][c] -> A-frag (rows n, k=c) direct 16B loads; W f32 [m][c] -> B-frag
// (k=c, col=m) direct 32B loads + cvt. Output tile [64 n][64 m], lane holds 4
// consecutive n at one m -> packed stores for modes 0/2; mode 1 ([n][d]) via a
// one-shot LDS transpose.
__global__ __launch_bounds__(256) void gemm_kernel(const float* __restrict__ Wf,
                                                   const float* __restrict__ bias,
                                                   const __bf16* __restrict__ XT,
                                                   __bf16* __restrict__ OUTb,
                                                   float* __restrict__ OUTf,
                                                   const float* __restrict__ RES,
                                                   int mode, float prescale) {
    const int n0 = blockIdx.x * 64;
    const int m0 = blockIdx.y * 64;
    const int b  = blockIdx.z;
    const int tid = threadIdx.x;
    const int w = tid >> 6, lane = tid & 63, quad = lane >> 4, l16 = lane & 15;

    __shared__ __bf16 T1[64][72];   // mode-1 epilogue transpose only

    f32x4 acc[4];
    #pragma unroll
    for (int j = 0; j < 4; j++) acc[j] = (f32x4){0.f, 0.f, 0.f, 0.f};

    const __bf16* ap  = XT + ((size_t)b * N_ + n0 + w * 16 + l16) * C_ + quad * 8;
    const float*  wp0 = Wf + (size_t)(m0 + l16) * C_ + quad * 8;

    for (int kc = 0; kc < C_; kc += 32) {
        bf16x8 afr = *(const bf16x8*)(ap + kc);
        #pragma unroll
        for (int j = 0; j < 4; j++) {
            const float* wp = wp0 + (size_t)j * 16 * C_ + kc;
            float4 w0 = *(const float4*)wp;
            float4 w1 = *(const float4*)(wp + 4);
            bf16x8 bfr;
            bfr[0] = (__bf16)w0.x; bfr[1] = (__bf16)w0.y; bfr[2] = (__bf16)w0.z; bfr[3] = (__bf16)w0.w;
            bfr[4] = (__bf16)w1.x; bfr[5] = (__bf16)w1.y; bfr[6] = (__bf16)w1.z; bfr[7] = (__bf16)w1.w;
            acc[j] = __builtin_amdgcn_mfma_f32_16x16x32_bf16(afr, bfr, acc[j], 0, 0, 0);
        }
    }

    const int nn = n0 + w * 16 + quad * 4;       // 4 consecutive n per lane (r=0..3)
    if (mode == 0) {                              // bf16 [c][n] (V for attention)
        #pragma unroll
        for (int j = 0; j < 4; j++) {
            const int m = m0 + j * 16 + l16;
            const float bi = bias[m];
            bf16x4 o;
            #pragma unroll
            for (int r = 0; r < 4; r++) o[r] = (__bf16)(acc[j][r] + bi);
            *(bf16x4*)(OUTb + (size_t)(b * C_ + m) * N_ + nn) = o;
        }
    } else if (mode == 2) {                       // f32 [c][n] + residual (final)
        #pragma unroll
        for (int j = 0; j < 4; j++) {
            const int m = m0 + j * 16 + l16;
            const float bi = bias[m];
            const size_t off = (size_t)(b * C_ + m) * N_ + nn;
            const float4 res = *(const float4*)(RES + off);
            f32x4 v;
            v[0] = acc[j][0] + bi + res.x;
            v[1] = acc[j][1] + bi + res.y;
            v[2] = acc[j][2] + bi + res.z;
            v[3] = acc[j][3] + bi + res.w;
            *(f32x4*)(OUTf + off) = v;
        }
    } else {                                      // mode 1: bf16 [bh][n][d] (Q/K)
        #pragma unroll
        for (int j = 0; j < 4; j++) {
            const int m = m0 + j * 16 + l16;
            const float bi = bias[m];
            #pragma unroll
            for (int r = 0; r < 4; r++)
                T1[w * 16 + quad * 4 + r][j * 16 + l16] = (__bf16)((acc[j][r] + bi) * prescale);
        }
        __syncthreads();
        const int h = m0 >> 6;
        const int row0 = tid >> 3, chh = (tid & 7) * 8;   // 8 threads x 8 elems = full 64-wide row
        #pragma unroll
        for (int i = 0; i < 2; i++) {
            const int row = row0 + i * 32;
            *(bf16x8*)(OUTb + ((size_t)(b * NH_ + h) * N_ + n0 + row) * HD_ + chh) =
                *(const bf16x8*)(&T1[row][chh]);
        }
    }
}

// ---------------- Flash attention v6: permlane P^T transpose, [n][c] output ------
// Core loop identical to v5. Epilogue writes O as [b][n][c] (q-major Ot tile,
// packed b64 LDS writes) so the Wo GEMM can consume it as direct A-fragments.
__global__ __launch_bounds__(256, 2) void attn_kernel(const __bf16* __restrict__ qT,  // [16][N][64], scale*log2e folded
                                                      const __bf16* __restrict__ kT,  // [16][N][64]
                                                      const __bf16* __restrict__ V,   // [4][256][N]
                                                      __bf16* __restrict__ O) {       // [4][N][256]
    const int flat = blockIdx.y * 32 + blockIdx.x;
    const int bh = flat & 15;          // XCD = flat%8 = bh%8 -> 2 bh per XCD (L2-resident K/V)
    const int qt = flat >> 4;
    const int q0 = qt * 128;
    const int b = bh >> 2, h = bh & 3;
    const int tid = threadIdx.x;
    const int w = tid >> 6, lane = tid & 63, quad = lane >> 4, l16 = lane & 15;

    __shared__ union SMem {
        struct { __bf16 K[2][64][72]; __bf16 Vt[2][64][72]; } kv;   // 36 KB dbuf
        __bf16 Ot[128][72];                                         // q-major, 18.4 KB
    } sm;

    const __bf16* qTb = qT + (size_t)bh * N_ * HD_;
    const __bf16* kTb = kT + (size_t)bh * N_ * HD_;
    const __bf16* Vb  = V + ((size_t)b * C_ + h * HD_) * N_;

    bf16x8 qa[2][2];
    #pragma unroll
    for (int qg = 0; qg < 2; qg++)
        #pragma unroll
        for (int kk = 0; kk < 2; kk++)
            qa[qg][kk] = *(const bf16x8*)(qTb + (size_t)(q0 + w * 32 + qg * 16 + l16) * HD_ + kk * 32 + quad * 8);

    f32x4 oacc[2][4];
    #pragma unroll
    for (int qg = 0; qg < 2; qg++)
        #pragma unroll
        for (int j = 0; j < 4; j++) oacc[qg][j] = (f32x4){0.f, 0.f, 0.f, 0.f};
    float lsum[2] = {0.f, 0.f};

    const int srow = tid >> 3;          // 0..31
    const int scol = (tid & 7) * 8;

    // preload tile 0 into registers
    bf16x8 rk[2], rv[2];
    #pragma unroll
    for (int i = 0; i < 2; i++) {
        const int row = srow + i * 32;
        rk[i] = *(const bf16x8*)(kTb + (size_t)row * HD_ + scol);
        rv[i] = *(const bf16x8*)(Vb + (size_t)row * N_ + scol);
    }

    for (int it = 0; it < N_ / 64; it++) {
        const int cur = it & 1;
        const int nm0 = ((it + 1) * 64) & (N_ - 1);   // wraps on last iter (harmless reload)
        #pragma unroll
        for (int i = 0; i < 2; i++) {
            const int row = srow + i * 32;
            *(bf16x8*)(&sm.kv.K[cur][row][scol])  = rk[i];
            *(bf16x8*)(&sm.kv.Vt[cur][row][scol]) = rv[i];
        }
        #pragma unroll
        for (int i = 0; i < 2; i++) {
            const int row = srow + i * 32;
            rk[i] = *(const bf16x8*)(kTb + (size_t)(nm0 + row) * HD_ + scol);
            rv[i] = *(const bf16x8*)(Vb + (size_t)row * N_ + nm0 + scol);
        }
        __syncthreads();
        bf16x8 kb[2][4], vb[2][4];
        #pragma unroll
        for (int kk = 0; kk < 2; kk++)
            #pragma unroll
            for (int j = 0; j < 4; j++) {
                kb[kk][j] = *(const bf16x8*)(&sm.kv.K[cur][j * 16 + l16][kk * 32 + quad * 8]);
                vb[kk][j] = *(const bf16x8*)(&sm.kv.Vt[cur][j * 16 + l16][kk * 32 + quad * 8]);
            }
        #pragma unroll
        for (int qg = 0; qg < 2; qg++) {
            f32x4 s[4];
            #pragma unroll
            for (int j = 0; j < 4; j++) s[j] = (f32x4){0.f, 0.f, 0.f, 0.f};
            #pragma unroll
            for (int kk = 0; kk < 2; kk++)
                #pragma unroll
                for (int j = 0; j < 4; j++)
                    s[j] = __builtin_amdgcn_mfma_f32_16x16x32_bf16(kb[kk][j], qa[qg][kk], s[j], 0, 0, 0);
            float p[4][4];
            float ls = 0.f;
            #pragma unroll
            for (int j = 0; j < 4; j++) {
                #pragma unroll
                for (int r = 0; r < 4; r++) p[j][r] = EXP2F(s[j][r]);
                ls += (p[j][0] + p[j][1]) + (p[j][2] + p[j][3]);
            }
            lsum[qg] += ls;
            unsigned int pk0[4], pk1[4];
            #pragma unroll
            for (int j = 0; j < 4; j++) {
                pk0[j] = packbf(p[j][0], p[j][1]);
                pk1[j] = packbf(p[j][2], p[j][3]);
            }
            // P^T -> B-frag via permlane swaps (VALU pipe, zero LDS traffic).
            #pragma unroll
            for (int kk = 0; kk < 2; kk++) {
                u32x2 t0 = __builtin_amdgcn_permlane32_swap(pk0[2 * kk], pk0[2 * kk + 1], false, false);
                u32x2 t1 = __builtin_amdgcn_permlane32_swap(pk1[2 * kk], pk1[2 * kk + 1], false, false);
                u32x2 a0 = __builtin_amdgcn_permlane16_swap(t0[0], t0[1], false, false);
                u32x2 a1 = __builtin_amdgcn_permlane16_swap(t1[0], t1[1], false, false);
                bf16x8 pb = __builtin_bit_cast(bf16x8, (u32x4){a0[0], a1[0], a0[1], a1[1]});
                #pragma unroll
                for (int jd = 0; jd < 4; jd++)
                    oacc[qg][jd] = __builtin_amdgcn_mfma_f32_16x16x32_bf16(vb[kk][jd], pb, oacc[qg][jd], 0, 0, 0);
            }
        }
    }
    // final softmax denominators (cross-quad reduce, once)
    float inv[2];
    #pragma unroll
    for (int qg = 0; qg < 2; qg++) {
        float l = lsum[qg];
        l += __shfl_xor(l, 16);
        l += __shfl_xor(l, 32);
        inv[qg] = 1.f / l;
    }
    __syncthreads();   // all kv reads done before Ot overwrites the union
    // Ot[q][d]: per lane per (qg,jd), 4 consecutive d -> packed b64 writes
    #pragma unroll
    for (int qg = 0; qg < 2; qg++) {
        #pragma unroll
        for (int jd = 0; jd < 4; jd++) {
            bf16x4 o;
            #pragma unroll
            for (int r = 0; r < 4; r++) o[r] = (__bf16)(oacc[qg][jd][r] * inv[qg]);
            *(bf16x4*)(&sm.Ot[w * 32 + qg * 16 + l16][jd * 16 + quad * 4]) = o;
        }
    }
    __syncthreads();
    // store O as [b][n][c]: 8 threads x bf16x8 = one full 64-wide row per group
    __bf16* Ob = O + ((size_t)b * N_ + q0) * C_ + h * HD_;
    const int row0 = tid >> 3, chh = (tid & 7) * 8;
    #pragma unroll
    for (int i = 0; i < 4; i++) {
        const int row = row0 + i * 32;
        *(bf16x8*)(Ob + (size_t)row * C_ + chh) = *(const bf16x8*)(&sm.Ot[row][chh]);
    }
}

extern "C" void kernel_launch(void* const* d_in, const int* in_sizes, int n_in,
                              void* d_out, int out_size, void* d_ws, size_t ws_size,
                              hipStream_t stream) {
    const float* x     = (const float*)d_in[0];
    const float* cond  = (const float*)d_in[1];
    const float* gnqw  = (const float*)d_in[2];
    const float* gnqb  = (const float*)d_in[3];
    const float* gnkw  = (const float*)d_in[4];
    const float* gnkb  = (const float*)d_in[5];
    const float* wq    = (const float*)d_in[6];
    const float* bq    = (const float*)d_in[7];
    const float* wk    = (const float*)d_in[8];
    const float* bk    = (const float*)d_in[9];
    const float* wv    = (const float*)d_in[10];
    const float* bv    = (const float*)d_in[11];
    const float* wo    = (const float*)d_in[12];
    const float* bo    = (const float*)d_in[13];
    float* out = (float*)d_out;

    const size_t TEN = (size_t)B_ * C_ * N_;
    __bf16* gnx   = (__bf16*)d_ws;      // [b][n][c]
    __bf16* gnc   = gnx + TEN;          // [b][n][c]
    __bf16* qT    = gnc + TEN;          // [bh][n][d]
    __bf16* kT    = qT  + TEN;          // [bh][n][d]
    __bf16* v     = kT  + TEN;          // [b][c][n]
    __bf16* attno = v   + TEN;          // [b][n][c]

    gn_kernel<<<dim3(B_ * G_), 256, 0, stream>>>(x,    gnqw, gnqb, gnx);
    gn_kernel<<<dim3(B_ * G_), 256, 0, stream>>>(cond, gnkw, gnkb, gnc);

    dim3 gg(N_ / 64, C_ / 64, B_);
    gemm_kernel<<<gg, 256, 0, stream>>>(wq, bq, gnx, qT, nullptr, nullptr, 1, 0.125f * 1.44269504088896f);
    gemm_kernel<<<gg, 256, 0, stream>>>(wk, bk, gnc, kT, nullptr, nullptr, 1, 1.0f);
    gemm_kernel<<<gg, 256, 0, stream>>>(wv, bv, gnc, v,  nullptr, nullptr, 0, 1.0f);

    attn_kernel<<<dim3(32, 16), 256, 0, stream>>>(qT, kT, v, attno);

    gemm_kernel<<<gg, 256, 0, stream>>>(wo, bo, attno, nullptr, out, x, 2, 1.0f);
}

// Round 6
// 321.745 us; speedup vs baseline: 1.1664x; 1.1664x over previous
//
#include <hip/hip_runtime.h>
#include <hip/hip_bf16.h>

#define B_   4
#define C_   256
#define N_   4096   // H*W
#define NH_  4
#define HD_  64
#define G_   32
#define CPG_ 8      // C_/G_
#define EPS_ 1e-5f

typedef __bf16 bf16x8 __attribute__((ext_vector_type(8)));
typedef __bf16 bf16x4 __attribute__((ext_vector_type(4)));
typedef float  f32x4  __attribute__((ext_vector_type(4)));
typedef unsigned int u32x4 __attribute__((ext_vector_type(4)));
typedef unsigned int u32x2 __attribute__((ext_vector_type(2)));

#define EXP2F(x) __builtin_amdgcn_exp2f(x)   // v_exp_f32: D = 2^S0

static __device__ __forceinline__ unsigned int packbf(float a, float b) {
    __bf16 x = (__bf16)a, y = (__bf16)b;
    unsigned short ux = __builtin_bit_cast(unsigned short, x);
    unsigned short uy = __builtin_bit_cast(unsigned short, y);
    return (unsigned int)ux | ((unsigned int)uy << 16);
}

// ---------------- W pre-conversion: f32 [m][c] -> bf16 [m][c], all 4 matrices ----
__global__ __launch_bounds__(256) void wconv_kernel(const float* __restrict__ w0,
                                                    const float* __restrict__ w1,
                                                    const float* __restrict__ w2,
                                                    const float* __restrict__ w3,
                                                    __bf16* __restrict__ dst) {
    const float* srcs[4] = {w0, w1, w2, w3};
    const float* s = srcs[blockIdx.y];
    __bf16* d = dst + (size_t)blockIdx.y * C_ * C_;
    const int i = blockIdx.x * 256 + threadIdx.x;        // float4 index, 64 blocks/matrix
    float4 v = ((const float4*)s)[i];
    bf16x4 o;
    o[0] = (__bf16)v.x; o[1] = (__bf16)v.y; o[2] = (__bf16)v.z; o[3] = (__bf16)v.w;
    ((bf16x4*)d)[i] = o;
}

// ---------------- GroupNorm: fp32 [b][c][n] -> normalized bf16 X^T [b][n][c] -----
// Transposed output makes GEMM A-fragments direct 16B loads (no LDS staging).
__global__ __launch_bounds__(256) void gn_kernel(const float* __restrict__ in,
                                                 const float* __restrict__ gw,
                                                 const float* __restrict__ gb,
                                                 __bf16* __restrict__ out) {
    const int b = blockIdx.x / G_;
    const int g = blockIdx.x % G_;
    const int tid = threadIdx.x;
    const size_t base = ((size_t)b * C_ + g * CPG_) * N_;
    const float4* pv = (const float4*)(in + base);
    const int NC = (CPG_ * N_) / 4;

    float s = 0.f, ss = 0.f;
    for (int i = tid; i < NC; i += 256) {
        float4 v = pv[i];
        s  += v.x + v.y + v.z + v.w;
        ss += v.x * v.x + v.y * v.y + v.z * v.z + v.w * v.w;
    }
    #pragma unroll
    for (int m = 32; m >= 1; m >>= 1) { s += __shfl_xor(s, m); ss += __shfl_xor(ss, m); }
    __shared__ float red[8];
    const int w = tid >> 6;
    if ((tid & 63) == 0) { red[w] = s; red[4 + w] = ss; }
    __syncthreads();
    s  = red[0] + red[1] + red[2] + red[3];
    ss = red[4] + red[5] + red[6] + red[7];
    const float mean = s * (1.f / 32768.f);
    const float var  = ss * (1.f / 32768.f) - mean * mean;
    const float rinv = rsqrtf(var + EPS_);

    // fold per-channel scale/shift: o = v*sc[j] + sh[j]
    float sc[CPG_], sh[CPG_];
    #pragma unroll
    for (int j = 0; j < CPG_; j++) {
        const float gm = gw[g * CPG_ + j], bt = gb[g * CPG_ + j];
        sc[j] = rinv * gm;
        sh[j] = bt - mean * rinv * gm;
    }
    __bf16* ob = out + (size_t)b * N_ * C_ + g * CPG_;
    for (int n = tid; n < N_; n += 256) {        // 16 iters; per-instr loads coalesce over n
        bf16x8 o;
        #pragma unroll
        for (int j = 0; j < CPG_; j++) {
            const float v = in[base + (size_t)j * N_ + n];
            o[j] = (__bf16)(v * sc[j] + sh[j]);
        }
        *(bf16x8*)(ob + (size_t)n * C_) = o;     // 16B per lane, L2 merges rows
    }
}

// ---------------- conv1x1 GEMM: LDS-free, pure bf16 loads + MFMA -----------------
// X^T [b][n][c] -> A-frag (rows n, k=c) direct 16B loads; Wb bf16 [m][c] ->
// B-frag (k=c, col=m) direct 16B loads (pre-converted, no inner-loop cvt).
// One-deep register prefetch of both fragments. Output tile [64 n][64 m].
__global__ __launch_bounds__(256) void gemm_kernel(const __bf16* __restrict__ Wb,
                                                   const float* __restrict__ bias,
                                                   const __bf16* __restrict__ XT,
                                                   __bf16* __restrict__ OUTb,
                                                   float* __restrict__ OUTf,
                                                   const float* __restrict__ RES,
                                                   int mode, float prescale) {
    const int n0 = blockIdx.x * 64;
    const int m0 = blockIdx.y * 64;
    const int b  = blockIdx.z;
    const int tid = threadIdx.x;
    const int w = tid >> 6, lane = tid & 63, quad = lane >> 4, l16 = lane & 15;

    __shared__ __bf16 T1[64][72];   // mode-1 epilogue transpose only

    f32x4 acc[4];
    #pragma unroll
    for (int j = 0; j < 4; j++) acc[j] = (f32x4){0.f, 0.f, 0.f, 0.f};

    const __bf16* ap  = XT + ((size_t)b * N_ + n0 + w * 16 + l16) * C_ + quad * 8;
    const __bf16* wp0 = Wb + (size_t)(m0 + l16) * C_ + quad * 8;

    bf16x8 a0 = *(const bf16x8*)ap;
    bf16x8 wv[4];
    #pragma unroll
    for (int j = 0; j < 4; j++) wv[j] = *(const bf16x8*)(wp0 + (size_t)j * 16 * C_);

    for (int kc = 0; kc < C_; kc += 32) {
        const int nk = (kc + 32) & (C_ - 1);     // wraps to 0 on last iter (harmless reload)
        bf16x8 a1 = *(const bf16x8*)(ap + nk);
        bf16x8 wn[4];
        #pragma unroll
        for (int j = 0; j < 4; j++) wn[j] = *(const bf16x8*)(wp0 + (size_t)j * 16 * C_ + nk);
        #pragma unroll
        for (int j = 0; j < 4; j++)
            acc[j] = __builtin_amdgcn_mfma_f32_16x16x32_bf16(a0, wv[j], acc[j], 0, 0, 0);
        a0 = a1;
        #pragma unroll
        for (int j = 0; j < 4; j++) wv[j] = wn[j];
    }

    const int nn = n0 + w * 16 + quad * 4;       // 4 consecutive n per lane (r=0..3)
    if (mode == 0) {                              // bf16 [c][n] (V for attention)
        #pragma unroll
        for (int j = 0; j < 4; j++) {
            const int m = m0 + j * 16 + l16;
            const float bi = bias[m];
            bf16x4 o;
            #pragma unroll
            for (int r = 0; r < 4; r++) o[r] = (__bf16)(acc[j][r] + bi);
            *(bf16x4*)(OUTb + (size_t)(b * C_ + m) * N_ + nn) = o;
        }
    } else if (mode == 2) {                       // f32 [c][n] + residual (final)
        #pragma unroll
        for (int j = 0; j < 4; j++) {
            const int m = m0 + j * 16 + l16;
            const float bi = bias[m];
            const size_t off = (size_t)(b * C_ + m) * N_ + nn;
            const float4 res = *(const float4*)(RES + off);
            f32x4 v;
            v[0] = acc[j][0] + bi + res.x;
            v[1] = acc[j][1] + bi + res.y;
            v[2] = acc[j][2] + bi + res.z;
            v[3] = acc[j][3] + bi + res.w;
            *(f32x4*)(OUTf + off) = v;
        }
    } else {                                      // mode 1: bf16 [bh][n][d] (Q/K)
        #pragma unroll
        for (int j = 0; j < 4; j++) {
            const int m = m0 + j * 16 + l16;
            const float bi = bias[m];
            #pragma unroll
            for (int r = 0; r < 4; r++)
                T1[w * 16 + quad * 4 + r][j * 16 + l16] = (__bf16)((acc[j][r] + bi) * prescale);
        }
        __syncthreads();
        const int h = m0 >> 6;
        const int row0 = tid >> 3, chh = (tid & 7) * 8;   // 8 threads x 8 elems = full 64-wide row
        #pragma unroll
        for (int i = 0; i < 2; i++) {
            const int row = row0 + i * 32;
            *(bf16x8*)(OUTb + ((size_t)(b * NH_ + h) * N_ + n0 + row) * HD_ + chh) =
                *(const bf16x8*)(&T1[row][chh]);
        }
    }
}

// ---------------- Flash attention v6: permlane P^T transpose, [n][c] output ------
// Core loop identical to v5. Epilogue writes O as [b][n][c] (q-major Ot tile,
// packed b64 LDS writes) so the Wo GEMM can consume it as direct A-fragments.
__global__ __launch_bounds__(256, 2) void attn_kernel(const __bf16* __restrict__ qT,  // [16][N][64], scale*log2e folded
                                                      const __bf16* __restrict__ kT,  // [16][N][64]
                                                      const __bf16* __restrict__ V,   // [4][256][N]
                                                      __bf16* __restrict__ O) {       // [4][N][256]
    const int flat = blockIdx.y * 32 + blockIdx.x;
    const int bh = flat & 15;          // XCD = flat%8 = bh%8 -> 2 bh per XCD (L2-resident K/V)
    const int qt = flat >> 4;
    const int q0 = qt * 128;
    const int b = bh >> 2, h = bh & 3;
    const int tid = threadIdx.x;
    const int w = tid >> 6, lane = tid & 63, quad = lane >> 4, l16 = lane & 15;

    __shared__ union SMem {
        struct { __bf16 K[2][64][72]; __bf16 Vt[2][64][72]; } kv;   // 36 KB dbuf
        __bf16 Ot[128][72];                                         // q-major, 18.4 KB
    } sm;

    const __bf16* qTb = qT + (size_t)bh * N_ * HD_;
    const __bf16* kTb = kT + (size_t)bh * N_ * HD_;
    const __bf16* Vb  = V + ((size_t)b * C_ + h * HD_) * N_;

    bf16x8 qa[2][2];
    #pragma unroll
    for (int qg = 0; qg < 2; qg++)
        #pragma unroll
        for (int kk = 0; kk < 2; kk++)
            qa[qg][kk] = *(const bf16x8*)(qTb + (size_t)(q0 + w * 32 + qg * 16 + l16) * HD_ + kk * 32 + quad * 8);

    f32x4 oacc[2][4];
    #pragma unroll
    for (int qg = 0; qg < 2; qg++)
        #pragma unroll
        for (int j = 0; j < 4; j++) oacc[qg][j] = (f32x4){0.f, 0.f, 0.f, 0.f};
    float lsum[2] = {0.f, 0.f};

    const int srow = tid >> 3;          // 0..31
    const int scol = (tid & 7) * 8;

    // preload tile 0 into registers
    bf16x8 rk[2], rv[2];
    #pragma unroll
    for (int i = 0; i < 2; i++) {
        const int row = srow + i * 32;
        rk[i] = *(const bf16x8*)(kTb + (size_t)row * HD_ + scol);
        rv[i] = *(const bf16x8*)(Vb + (size_t)row * N_ + scol);
    }

    for (int it = 0; it < N_ / 64; it++) {
        const int cur = it & 1;
        const int nm0 = ((it + 1) * 64) & (N_ - 1);   // wraps on last iter (harmless reload)
        #pragma unroll
        for (int i = 0; i < 2; i++) {
            const int row = srow + i * 32;
            *(bf16x8*)(&sm.kv.K[cur][row][scol])  = rk[i];
            *(bf16x8*)(&sm.kv.Vt[cur][row][scol]) = rv[i];
        }
        #pragma unroll
        for (int i = 0; i < 2; i++) {
            const int row = srow + i * 32;
            rk[i] = *(const bf16x8*)(kTb + (size_t)(nm0 + row) * HD_ + scol);
            rv[i] = *(const bf16x8*)(Vb + (size_t)row * N_ + nm0 + scol);
        }
        __syncthreads();
        bf16x8 kb[2][4], vb[2][4];
        #pragma unroll
        for (int kk = 0; kk < 2; kk++)
            #pragma unroll
            for (int j = 0; j < 4; j++) {
                kb[kk][j] = *(const bf16x8*)(&sm.kv.K[cur][j * 16 + l16][kk * 32 + quad * 8]);
                vb[kk][j] = *(const bf16x8*)(&sm.kv.Vt[cur][j * 16 + l16][kk * 32 + quad * 8]);
            }
        #pragma unroll
        for (int qg = 0; qg < 2; qg++) {
            f32x4 s[4];
            #pragma unroll
            for (int j = 0; j < 4; j++) s[j] = (f32x4){0.f, 0.f, 0.f, 0.f};
            #pragma unroll
            for (int kk = 0; kk < 2; kk++)
                #pragma unroll
                for (int j = 0; j < 4; j++)
                    s[j] = __builtin_amdgcn_mfma_f32_16x16x32_bf16(kb[kk][j], qa[qg][kk], s[j], 0, 0, 0);
            float p[4][4];
            float ls = 0.f;
            #pragma unroll
            for (int j = 0; j < 4; j++) {
                #pragma unroll
                for (int r = 0; r < 4; r++) p[j][r] = EXP2F(s[j][r]);
                ls += (p[j][0] + p[j][1]) + (p[j][2] + p[j][3]);
            }
            lsum[qg] += ls;
            unsigned int pk0[4], pk1[4];
            #pragma unroll
            for (int j = 0; j < 4; j++) {
                pk0[j] = packbf(p[j][0], p[j][1]);
                pk1[j] = packbf(p[j][2], p[j][3]);
            }
            // P^T -> B-frag via permlane swaps (VALU pipe, zero LDS traffic).
            #pragma unroll
            for (int kk = 0; kk < 2; kk++) {
                u32x2 t0 = __builtin_amdgcn_permlane32_swap(pk0[2 * kk], pk0[2 * kk + 1], false, false);
                u32x2 t1 = __builtin_amdgcn_permlane32_swap(pk1[2 * kk], pk1[2 * kk + 1], false, false);
                u32x2 a0 = __builtin_amdgcn_permlane16_swap(t0[0], t0[1], false, false);
                u32x2 a1 = __builtin_amdgcn_permlane16_swap(t1[0], t1[1], false, false);
                bf16x8 pb = __builtin_bit_cast(bf16x8, (u32x4){a0[0], a1[0], a0[1], a1[1]});
                #pragma unroll
                for (int jd = 0; jd < 4; jd++)
                    oacc[qg][jd] = __builtin_amdgcn_mfma_f32_16x16x32_bf16(vb[kk][jd], pb, oacc[qg][jd], 0, 0, 0);
            }
        }
    }
    // final softmax denominators (cross-quad reduce, once)
    float inv[2];
    #pragma unroll
    for (int qg = 0; qg < 2; qg++) {
        float l = lsum[qg];
        l += __shfl_xor(l, 16);
        l += __shfl_xor(l, 32);
        inv[qg] = 1.f / l;
    }
    __syncthreads();   // all kv reads done before Ot overwrites the union
    // Ot[q][d]: per lane per (qg,jd), 4 consecutive d -> packed b64 writes
    #pragma unroll
    for (int qg = 0; qg < 2; qg++) {
        #pragma unroll
        for (int jd = 0; jd < 4; jd++) {
            bf16x4 o;
            #pragma unroll
            for (int r = 0; r < 4; r++) o[r] = (__bf16)(oacc[qg][jd][r] * inv[qg]);
            *(bf16x4*)(&sm.Ot[w * 32 + qg * 16 + l16][jd * 16 + quad * 4]) = o;
        }
    }
    __syncthreads();
    // store O as [b][n][c]: 8 threads x bf16x8 = one full 64-wide row per group
    __bf16* Ob = O + ((size_t)b * N_ + q0) * C_ + h * HD_;
    const int row0 = tid >> 3, chh = (tid & 7) * 8;
    #pragma unroll
    for (int i = 0; i < 4; i++) {
        const int row = row0 + i * 32;
        *(bf16x8*)(Ob + (size_t)row * C_ + chh) = *(const bf16x8*)(&sm.Ot[row][chh]);
    }
}

extern "C" void kernel_launch(void* const* d_in, const int* in_sizes, int n_in,
                              void* d_out, int out_size, void* d_ws, size_t ws_size,
                              hipStream_t stream) {
    const float* x     = (const float*)d_in[0];
    const float* cond  = (const float*)d_in[1];
    const float* gnqw  = (const float*)d_in[2];
    const float* gnqb  = (const float*)d_in[3];
    const float* gnkw  = (const float*)d_in[4];
    const float* gnkb  = (const float*)d_in[5];
    const float* wq    = (const float*)d_in[6];
    const float* bq    = (const float*)d_in[7];
    const float* wk    = (const float*)d_in[8];
    const float* bk    = (const float*)d_in[9];
    const float* wv    = (const float*)d_in[10];
    const float* bv    = (const float*)d_in[11];
    const float* wo    = (const float*)d_in[12];
    const float* bo    = (const float*)d_in[13];
    float* out = (float*)d_out;

    const size_t TEN = (size_t)B_ * C_ * N_;
    __bf16* gnx   = (__bf16*)d_ws;      // [b][n][c]
    __bf16* gnc   = gnx + TEN;          // [b][n][c]
    __bf16* qT    = gnc + TEN;          // [bh][n][d]
    __bf16* kT    = qT  + TEN;          // [bh][n][d]
    __bf16* v     = kT  + TEN;          // [b][c][n]
    __bf16* attno = v   + TEN;          // [b][n][c]
    __bf16* wb    = attno + TEN;        // 4x [256][256] bf16 (q,k,v,o)

    wconv_kernel<<<dim3(64, 4), 256, 0, stream>>>(wq, wk, wv, wo, wb);

    gn_kernel<<<dim3(B_ * G_), 256, 0, stream>>>(x,    gnqw, gnqb, gnx);
    gn_kernel<<<dim3(B_ * G_), 256, 0, stream>>>(cond, gnkw, gnkb, gnc);

    const size_t WSZ = (size_t)C_ * C_;
    dim3 gg(N_ / 64, C_ / 64, B_);
    gemm_kernel<<<gg, 256, 0, stream>>>(wb,           bq, gnx, qT, nullptr, nullptr, 1, 0.125f * 1.44269504088896f);
    gemm_kernel<<<gg, 256, 0, stream>>>(wb + WSZ,     bk, gnc, kT, nullptr, nullptr, 1, 1.0f);
    gemm_kernel<<<gg, 256, 0, stream>>>(wb + 2 * WSZ, bv, gnc, v,  nullptr, nullptr, 0, 1.0f);

    attn_kernel<<<dim3(32, 16), 256, 0, stream>>>(qT, kT, v, attno);

    gemm_kernel<<<gg, 256, 0, stream>>>(wb + 3 * WSZ, bo, attno, nullptr, out, x, 2, 1.0f);
}

// Round 9
// 267.864 us; speedup vs baseline: 1.4010x; 1.2011x over previous
//
#include <hip/hip_runtime.h>
#include <hip/hip_bf16.h>

#define B_   4
#define C_   256
#define N_   4096   // H*W
#define NH_  4
#define HD_  64
#define G_   32
#define CPG_ 8      // C_/G_
#define EPS_ 1e-5f

typedef __bf16 bf16x8 __attribute__((ext_vector_type(8)));
typedef __bf16 bf16x4 __attribute__((ext_vector_type(4)));
typedef float  f32x4  __attribute__((ext_vector_type(4)));
typedef unsigned int u32x4 __attribute__((ext_vector_type(4)));
typedef unsigned int u32x2 __attribute__((ext_vector_type(2)));

#define EXP2F(x) __builtin_amdgcn_exp2f(x)   // v_exp_f32: D = 2^S0

static __device__ __forceinline__ unsigned int packbf(float a, float b) {
    __bf16 x = (__bf16)a, y = (__bf16)b;
    unsigned short ux = __builtin_bit_cast(unsigned short, x);
    unsigned short uy = __builtin_bit_cast(unsigned short, y);
    return (unsigned int)ux | ((unsigned int)uy << 16);
}

// ---------------- W pre-conversion: f32 [m][c] -> bf16 [m][c], all 4 matrices ----
__global__ __launch_bounds__(256) void wconv_kernel(const float* __restrict__ w0,
                                                    const float* __restrict__ w1,
                                                    const float* __restrict__ w2,
                                                    const float* __restrict__ w3,
                                                    __bf16* __restrict__ dst) {
    const float* srcs[4] = {w0, w1, w2, w3};
    const float* s = srcs[blockIdx.y];
    __bf16* d = dst + (size_t)blockIdx.y * C_ * C_;
    const int i = blockIdx.x * 256 + threadIdx.x;        // float4 index, 64 blocks/matrix
    float4 v = ((const float4*)s)[i];
    bf16x4 o;
    o[0] = (__bf16)v.x; o[1] = (__bf16)v.y; o[2] = (__bf16)v.z; o[3] = (__bf16)v.w;
    ((bf16x4*)d)[i] = o;
}

// ---------------- GroupNorm: fp32 [b][c][n] -> normalized bf16 X^T [b][n][c] -----
__global__ __launch_bounds__(256) void gn_kernel(const float* __restrict__ in,
                                                 const float* __restrict__ gw,
                                                 const float* __restrict__ gb,
                                                 __bf16* __restrict__ out) {
    const int b = blockIdx.x / G_;
    const int g = blockIdx.x % G_;
    const int tid = threadIdx.x;
    const size_t base = ((size_t)b * C_ + g * CPG_) * N_;
    const float4* pv = (const float4*)(in + base);
    const int NC = (CPG_ * N_) / 4;

    float s = 0.f, ss = 0.f;
    for (int i = tid; i < NC; i += 256) {
        float4 v = pv[i];
        s  += v.x + v.y + v.z + v.w;
        ss += v.x * v.x + v.y * v.y + v.z * v.z + v.w * v.w;
    }
    #pragma unroll
    for (int m = 32; m >= 1; m >>= 1) { s += __shfl_xor(s, m); ss += __shfl_xor(ss, m); }
    __shared__ float red[8];
    const int w = tid >> 6;
    if ((tid & 63) == 0) { red[w] = s; red[4 + w] = ss; }
    __syncthreads();
    s  = red[0] + red[1] + red[2] + red[3];
    ss = red[4] + red[5] + red[6] + red[7];
    const float mean = s * (1.f / 32768.f);
    const float var  = ss * (1.f / 32768.f) - mean * mean;
    const float rinv = rsqrtf(var + EPS_);

    float sc[CPG_], sh[CPG_];
    #pragma unroll
    for (int j = 0; j < CPG_; j++) {
        const float gm = gw[g * CPG_ + j], bt = gb[g * CPG_ + j];
        sc[j] = rinv * gm;
        sh[j] = bt - mean * rinv * gm;
    }
    __bf16* ob = out + (size_t)b * N_ * C_ + g * CPG_;
    for (int n = tid; n < N_; n += 256) {
        bf16x8 o;
        #pragma unroll
        for (int j = 0; j < CPG_; j++) {
            const float v = in[base + (size_t)j * N_ + n];
            o[j] = (__bf16)(v * sc[j] + sh[j]);
        }
        *(bf16x8*)(ob + (size_t)n * C_) = o;
    }
}

// ---------------- conv1x1 GEMM: W-stationary in LDS ------------------------------
// Tile 64n x 128m x K=256. W slice (64KB bf16) staged ONCE into LDS; all 16
// A-fragments (256B/lane) issued upfront into registers; main loop is pure
// ds_read_b128 + MFMA (no global loads, no barriers). 2x2 wave grid.
__global__ __launch_bounds__(256) void gemm_kernel(const __bf16* __restrict__ Wb,
                                                   const float* __restrict__ bias,
                                                   const __bf16* __restrict__ XT,
                                                   __bf16* __restrict__ OUTb,
                                                   float* __restrict__ OUTf,
                                                   const float* __restrict__ RES,
                                                   int mode, float prescale) {
    const int n0 = blockIdx.x * 64;
    const int m0 = blockIdx.y * 128;
    const int b  = blockIdx.z;
    const int tid = threadIdx.x;
    const int w = tid >> 6, lane = tid & 63, quad = lane >> 4, l16 = lane & 15;
    const int wn = (w >> 1) * 32;        // wave n-offset (0/32)
    const int wm = (w & 1) * 64;         // wave m-offset (0/64)

    __shared__ union {
        __bf16 Wl[128][264];             // W tile [m][k], stride 264 (16B-aligned, bank floor)
        __bf16 T1[64][136];              // mode-1 epilogue transpose (overlays Wl)
    } sm;

    // ---- stage W[m0..m0+128)[0..256) -> LDS (64KB, coalesced 16B/lane) ----
    const __bf16* wsrc = Wb + (size_t)m0 * C_;
    #pragma unroll
    for (int i = 0; i < 16; i++) {
        const int e = i * 256 + tid;     // 16B-unit index, 4096 units
        const int row = e >> 5;          // 32 units per 256-wide row
        const int c8 = (e & 31) * 8;
        *(bf16x8*)(&sm.Wl[row][c8]) = *(const bf16x8*)(wsrc + (size_t)row * C_ + c8);
    }

    // ---- issue ALL A-fragments upfront (latency hides under staging+barrier) ----
    const __bf16* ap0 = XT + ((size_t)b * N_ + n0 + wn + l16) * C_ + quad * 8;
    const __bf16* ap1 = ap0 + (size_t)16 * C_;
    bf16x8 areg[2][8];
    #pragma unroll
    for (int ks = 0; ks < 8; ks++) {
        areg[0][ks] = *(const bf16x8*)(ap0 + ks * 32);
        areg[1][ks] = *(const bf16x8*)(ap1 + ks * 32);
    }

    f32x4 acc[2][4];
    #pragma unroll
    for (int qg = 0; qg < 2; qg++)
        #pragma unroll
        for (int jm = 0; jm < 4; jm++) acc[qg][jm] = (f32x4){0.f, 0.f, 0.f, 0.f};

    __syncthreads();

    // ---- main loop: pure LDS + MFMA ----
    #pragma unroll
    for (int ks = 0; ks < 8; ks++) {
        const int kc = ks * 32;
        #pragma unroll
        for (int jm = 0; jm < 4; jm++) {
            bf16x8 bw = *(const bf16x8*)(&sm.Wl[wm + jm * 16 + l16][kc + quad * 8]);
            acc[0][jm] = __builtin_amdgcn_mfma_f32_16x16x32_bf16(areg[0][ks], bw, acc[0][jm], 0, 0, 0);
            acc[1][jm] = __builtin_amdgcn_mfma_f32_16x16x32_bf16(areg[1][ks], bw, acc[1][jm], 0, 0, 0);
        }
    }

    // ---- epilogues ----
    if (mode == 0) {                              // bf16 [c][n] (V for attention)
        #pragma unroll
        for (int qg = 0; qg < 2; qg++) {
            const int nn = n0 + wn + qg * 16 + quad * 4;
            #pragma unroll
            for (int jm = 0; jm < 4; jm++) {
                const int m = m0 + wm + jm * 16 + l16;
                const float bi = bias[m];
                bf16x4 o;
                #pragma unroll
                for (int r = 0; r < 4; r++) o[r] = (__bf16)(acc[qg][jm][r] + bi);
                *(bf16x4*)(OUTb + (size_t)(b * C_ + m) * N_ + nn) = o;
            }
        }
    } else if (mode == 2) {                       // f32 [c][n] + residual (final)
        #pragma unroll
        for (int qg = 0; qg < 2; qg++) {
            const int nn = n0 + wn + qg * 16 + quad * 4;
            #pragma unroll
            for (int jm = 0; jm < 4; jm++) {
                const int m = m0 + wm + jm * 16 + l16;
                const float bi = bias[m];
                const size_t off = (size_t)(b * C_ + m) * N_ + nn;
                const float4 res = *(const float4*)(RES + off);
                f32x4 v;
                v[0] = acc[qg][jm][0] + bi + res.x;
                v[1] = acc[qg][jm][1] + bi + res.y;
                v[2] = acc[qg][jm][2] + bi + res.z;
                v[3] = acc[qg][jm][3] + bi + res.w;
                *(f32x4*)(OUTf + off) = v;
            }
        }
    } else {                                      // mode 1: bf16 [bh][n][d] (Q/K)
        __syncthreads();                          // all Wl reads done before overlay
        #pragma unroll
        for (int qg = 0; qg < 2; qg++)
            #pragma unroll
            for (int jm = 0; jm < 4; jm++) {
                const int m = m0 + wm + jm * 16 + l16;
                const float bi = bias[m];
                #pragma unroll
                for (int r = 0; r < 4; r++)
                    sm.T1[wn + qg * 16 + quad * 4 + r][wm + jm * 16 + l16] =
                        (__bf16)((acc[qg][jm][r] + bi) * prescale);
            }
        __syncthreads();
        const int h0 = m0 >> 6;                   // first head of this m-slice
        #pragma unroll
        for (int i = 0; i < 4; i++) {
            const int idx = i * 256 + tid;        // 0..1023
            const int row = idx >> 4;             // 0..63
            const int c = (idx & 15) * 8;         // 0..120
            const int hh = h0 + (c >> 6);
            const int d = c & 63;
            *(bf16x8*)(OUTb + ((size_t)(b * NH_ + hh) * N_ + n0 + row) * HD_ + d) =
                *(const bf16x8*)(&sm.T1[row][c]);
        }
    }
}

// ---------------- Flash attention v6: permlane P^T transpose, [n][c] output ------
__global__ __launch_bounds__(256, 2) void attn_kernel(const __bf16* __restrict__ qT,  // [16][N][64], scale*log2e folded
                                                      const __bf16* __restrict__ kT,  // [16][N][64]
                                                      const __bf16* __restrict__ V,   // [4][256][N]
                                                      __bf16* __restrict__ O) {       // [4][N][256]
    const int flat = blockIdx.y * 32 + blockIdx.x;
    const int bh = flat & 15;          // XCD = flat%8 = bh%8 -> 2 bh per XCD (L2-resident K/V)
    const int qt = flat >> 4;
    const int q0 = qt * 128;
    const int b = bh >> 2, h = bh & 3;
    const int tid = threadIdx.x;
    const int w = tid >> 6, lane = tid & 63, quad = lane >> 4, l16 = lane & 15;

    __shared__ union SMem {
        struct { __bf16 K[2][64][72]; __bf16 Vt[2][64][72]; } kv;   // 36 KB dbuf
        __bf16 Ot[128][72];                                         // q-major, 18.4 KB
    } sm;

    const __bf16* qTb = qT + (size_t)bh * N_ * HD_;
    const __bf16* kTb = kT + (size_t)bh * N_ * HD_;
    const __bf16* Vb  = V + ((size_t)b * C_ + h * HD_) * N_;

    bf16x8 qa[2][2];
    #pragma unroll
    for (int qg = 0; qg < 2; qg++)
        #pragma unroll
        for (int kk = 0; kk < 2; kk++)
            qa[qg][kk] = *(const bf16x8*)(qTb + (size_t)(q0 + w * 32 + qg * 16 + l16) * HD_ + kk * 32 + quad * 8);

    f32x4 oacc[2][4];
    #pragma unroll
    for (int qg = 0; qg < 2; qg++)
        #pragma unroll
        for (int j = 0; j < 4; j++) oacc[qg][j] = (f32x4){0.f, 0.f, 0.f, 0.f};
    float lsum[2] = {0.f, 0.f};

    const int srow = tid >> 3;          // 0..31
    const int scol = (tid & 7) * 8;

    bf16x8 rk[2], rv[2];
    #pragma unroll
    for (int i = 0; i < 2; i++) {
        const int row = srow + i * 32;
        rk[i] = *(const bf16x8*)(kTb + (size_t)row * HD_ + scol);
        rv[i] = *(const bf16x8*)(Vb + (size_t)row * N_ + scol);
    }

    for (int it = 0; it < N_ / 64; it++) {
        const int cur = it & 1;
        const int nm0 = ((it + 1) * 64) & (N_ - 1);   // wraps on last iter (harmless reload)
        #pragma unroll
        for (int i = 0; i < 2; i++) {
            const int row = srow + i * 32;
            *(bf16x8*)(&sm.kv.K[cur][row][scol])  = rk[i];
            *(bf16x8*)(&sm.kv.Vt[cur][row][scol]) = rv[i];
        }
        #pragma unroll
        for (int i = 0; i < 2; i++) {
            const int row = srow + i * 32;
            rk[i] = *(const bf16x8*)(kTb + (size_t)(nm0 + row) * HD_ + scol);
            rv[i] = *(const bf16x8*)(Vb + (size_t)row * N_ + nm0 + scol);
        }
        __syncthreads();
        bf16x8 kb[2][4], vb[2][4];
        #pragma unroll
        for (int kk = 0; kk < 2; kk++)
            #pragma unroll
            for (int j = 0; j < 4; j++) {
                kb[kk][j] = *(const bf16x8*)(&sm.kv.K[cur][j * 16 + l16][kk * 32 + quad * 8]);
                vb[kk][j] = *(const bf16x8*)(&sm.kv.Vt[cur][j * 16 + l16][kk * 32 + quad * 8]);
            }
        #pragma unroll
        for (int qg = 0; qg < 2; qg++) {
            f32x4 s[4];
            #pragma unroll
            for (int j = 0; j < 4; j++) s[j] = (f32x4){0.f, 0.f, 0.f, 0.f};
            #pragma unroll
            for (int kk = 0; kk < 2; kk++)
                #pragma unroll
                for (int j = 0; j < 4; j++)
                    s[j] = __builtin_amdgcn_mfma_f32_16x16x32_bf16(kb[kk][j], qa[qg][kk], s[j], 0, 0, 0);
            float p[4][4];
            float ls = 0.f;
            #pragma unroll
            for (int j = 0; j < 4; j++) {
                #pragma unroll
                for (int r = 0; r < 4; r++) p[j][r] = EXP2F(s[j][r]);
                ls += (p[j][0] + p[j][1]) + (p[j][2] + p[j][3]);
            }
            lsum[qg] += ls;
            unsigned int pk0[4], pk1[4];
            #pragma unroll
            for (int j = 0; j < 4; j++) {
                pk0[j] = packbf(p[j][0], p[j][1]);
                pk1[j] = packbf(p[j][2], p[j][3]);
            }
            #pragma unroll
            for (int kk = 0; kk < 2; kk++) {
                u32x2 t0 = __builtin_amdgcn_permlane32_swap(pk0[2 * kk], pk0[2 * kk + 1], false, false);
                u32x2 t1 = __builtin_amdgcn_permlane32_swap(pk1[2 * kk], pk1[2 * kk + 1], false, false);
                u32x2 a0 = __builtin_amdgcn_permlane16_swap(t0[0], t0[1], false, false);
                u32x2 a1 = __builtin_amdgcn_permlane16_swap(t1[0], t1[1], false, false);
                bf16x8 pb = __builtin_bit_cast(bf16x8, (u32x4){a0[0], a1[0], a0[1], a1[1]});
                #pragma unroll
                for (int jd = 0; jd < 4; jd++)
                    oacc[qg][jd] = __builtin_amdgcn_mfma_f32_16x16x32_bf16(vb[kk][jd], pb, oacc[qg][jd], 0, 0, 0);
            }
        }
    }
    float inv[2];
    #pragma unroll
    for (int qg = 0; qg < 2; qg++) {
        float l = lsum[qg];
        l += __shfl_xor(l, 16);
        l += __shfl_xor(l, 32);
        inv[qg] = 1.f / l;
    }
    __syncthreads();
    #pragma unroll
    for (int qg = 0; qg < 2; qg++) {
        #pragma unroll
        for (int jd = 0; jd < 4; jd++) {
            bf16x4 o;
            #pragma unroll
            for (int r = 0; r < 4; r++) o[r] = (__bf16)(oacc[qg][jd][r] * inv[qg]);
            *(bf16x4*)(&sm.Ot[w * 32 + qg * 16 + l16][jd * 16 + quad * 4]) = o;
        }
    }
    __syncthreads();
    __bf16* Ob = O + ((size_t)b * N_ + q0) * C_ + h * HD_;
    const int row0 = tid >> 3, chh = (tid & 7) * 8;
    #pragma unroll
    for (int i = 0; i < 4; i++) {
        const int row = row0 + i * 32;
        *(bf16x8*)(Ob + (size_t)row * C_ + chh) = *(const bf16x8*)(&sm.Ot[row][chh]);
    }
}

extern "C" void kernel_launch(void* const* d_in, const int* in_sizes, int n_in,
                              void* d_out, int out_size, void* d_ws, size_t ws_size,
                              hipStream_t stream) {
    const float* x     = (const float*)d_in[0];
    const float* cond  = (const float*)d_in[1];
    const float* gnqw  = (const float*)d_in[2];
    const float* gnqb  = (const float*)d_in[3];
    const float* gnkw  = (const float*)d_in[4];
    const float* gnkb  = (const float*)d_in[5];
    const float* wq    = (const float*)d_in[6];
    const float* bq    = (const float*)d_in[7];
    const float* wk    = (const float*)d_in[8];
    const float* bk    = (const float*)d_in[9];
    const float* wv    = (const float*)d_in[10];
    const float* bv    = (const float*)d_in[11];
    const float* wo    = (const float*)d_in[12];
    const float* bo    = (const float*)d_in[13];
    float* out = (float*)d_out;

    const size_t TEN = (size_t)B_ * C_ * N_;
    __bf16* gnx   = (__bf16*)d_ws;      // [b][n][c]
    __bf16* gnc   = gnx + TEN;          // [b][n][c]
    __bf16* qT    = gnc + TEN;          // [bh][n][d]
    __bf16* kT    = qT  + TEN;          // [bh][n][d]
    __bf16* v     = kT  + TEN;          // [b][c][n]
    __bf16* attno = v   + TEN;          // [b][n][c]
    __bf16* wb    = attno + TEN;        // 4x [256][256] bf16 (q,k,v,o)

    wconv_kernel<<<dim3(64, 4), 256, 0, stream>>>(wq, wk, wv, wo, wb);

    gn_kernel<<<dim3(B_ * G_), 256, 0, stream>>>(x,    gnqw, gnqb, gnx);
    gn_kernel<<<dim3(B_ * G_), 256, 0, stream>>>(cond, gnkw, gnkb, gnc);

    const size_t WSZ = (size_t)C_ * C_;
    dim3 gg(N_ / 64, C_ / 128, B_);
    gemm_kernel<<<gg, 256, 0, stream>>>(wb,           bq, gnx, qT, nullptr, nullptr, 1, 0.125f * 1.44269504088896f);
    gemm_kernel<<<gg, 256, 0, stream>>>(wb + WSZ,     bk, gnc, kT, nullptr, nullptr, 1, 1.0f);
    gemm_kernel<<<gg, 256, 0, stream>>>(wb + 2 * WSZ, bv, gnc, v,  nullptr, nullptr, 0, 1.0f);

    attn_kernel<<<dim3(32, 16), 256, 0, stream>>>(qT, kT, v, attno);

    gemm_kernel<<<gg, 256, 0, stream>>>(wb + 3 * WSZ, bo, attno, nullptr, out, x, 2, 1.0f);
}